// Round 4
// baseline (140.517 us; speedup 1.0000x reference)
//
#include <hip/hip_runtime.h>

// LyapunovSDELayer: out[i, t] = f^t(lam0[i]), f(x) = clip(x + 0.5*(0.3 - x), 0, 1)
// lam0 in [0,1) => clip never fires; affine closed form:
//   lam_t = 0.3 + 2^-t * (lam0 - 0.3)   (exact 2^-t via v_ldexp_f32; deviation
// from the iterated fp32 scan is contraction-damped, << 2e-2 threshold).
//
// Pure write-BW kernel: 134 MB mandatory output traffic; floor ~20 us at the
// 6.6 TB/s measured write ceiling. This revision: nontemporal (nt) stores to
// bypass L2 write-allocate on the write-once output, and 8 rows per wave
// (8 KB contiguous per wave, 16384 waves). NOTE: __builtin_nontemporal_store
// requires a clang ext_vector_type, not HIP's float4 class — use vfloat4.

typedef float vfloat4 __attribute__((ext_vector_type(4)));

__global__ __launch_bounds__(256) void lyap_h256_kernel(
    const float* __restrict__ lam0, float* __restrict__ out, int n_rows) {
    int g    = blockIdx.x * 256 + threadIdx.x;
    int lane = threadIdx.x & 63;
    int wave = g >> 6;                 // global wave id
    int row0 = wave << 3;              // 8 rows per wave
    if (row0 >= n_rows) return;
    int t0   = lane << 2;              // 0,4,...,252

    vfloat4* dst = (vfloat4*)(out + ((size_t)row0 << 8)) + lane;   // row0*256 + t0

#pragma unroll
    for (int r = 0; r < 8; ++r) {
        float lam = lam0[row0 + r];    // wave-uniform broadcast load (L1-hot)
        float dd  = ldexpf(lam - 0.3f, -t0);
        vfloat4 v;
        v.x = 0.3f + dd;
        v.y = fmaf(dd, 0.5f,   0.3f);
        v.z = fmaf(dd, 0.25f,  0.3f);
        v.w = fmaf(dd, 0.125f, 0.3f);
        if (t0 == 0) v.x = lam;        // column 0 is the raw input
        __builtin_nontemporal_store(v, dst + ((size_t)r << 6));  // nt: skip L2 alloc
    }
}

// Generic fallback (any H) — not hit for this problem's H=256.
__global__ __launch_bounds__(256) void lyap_scalar_kernel(
    const float* __restrict__ lam0, float* __restrict__ out,
    int n_rows, int H) {
    long long g = (long long)blockIdx.x * blockDim.x + threadIdx.x;
    long long total = (long long)n_rows * H;
    if (g >= total) return;
    int row = (int)(g / H);
    int t   = (int)(g - (long long)row * H);
    float lam = lam0[row];
    out[g] = (t == 0) ? lam : (0.3f + ldexpf(lam - 0.3f, -t));
}

extern "C" void kernel_launch(void* const* d_in, const int* in_sizes, int n_in,
                              void* d_out, int out_size, void* d_ws, size_t ws_size,
                              hipStream_t stream) {
    const float* lam0 = (const float*)d_in[0];
    float* out = (float*)d_out;
    int n_rows = in_sizes[0];               // 131072
    int H = out_size / n_rows;              // 256

    if (H == 256 && (n_rows & 7) == 0) {
        int waves = n_rows >> 3;            // 8 rows per wave -> 16384 waves
        int threads = waves * 64;
        int block = 256;
        int grid = (threads + block - 1) / block;   // 4096 blocks
        lyap_h256_kernel<<<grid, block, 0, stream>>>(lam0, out, n_rows);
    } else {
        long long total = (long long)n_rows * H;
        int block = 256;
        int grid = (int)((total + block - 1) / block);
        lyap_scalar_kernel<<<grid, block, 0, stream>>>(lam0, out, n_rows, H);
    }
}